// Round 1
// baseline (173.694 us; speedup 1.0000x reference)
//
#include <hip/hip_runtime.h>
#include <math.h>

#define Bn 4
#define Tn 12
#define Nn 512
#define Dn 128
#define Ln 4
#define Hn 64
#define NNe (Nn*Nn)

// ---------------- K1: lag encoder + mean-agg + src/tgt projection ----------------
#define ROWS 8
__global__ __launch_bounds__(256) void k_encode(
    const float* __restrict__ x, const float* __restrict__ W1, const float* __restrict__ b1,
    const float* __restrict__ W2, const float* __restrict__ b2,
    const float* __restrict__ Ws1, const float* __restrict__ bs1,
    float* __restrict__ sp, float* __restrict__ tp, unsigned int* __restrict__ maxslot)
{
    __shared__ float xs[ROWS][Ln][Dn];     // 16 KB
    __shared__ float wbuf[Dn*Hn];          // 32 KB (W1[l] then W2[l])
    __shared__ float hbuf[ROWS][Hn];       // 2 KB
    __shared__ float aggbuf[ROWS][Dn];     // 4 KB
    int tid = threadIdx.x;
    if (blockIdx.x == 0 && tid < Bn) maxslot[tid] = 0u;   // zero per-batch max slots
    int r0 = blockIdx.x * ROWS;

    // stage the 4 lag slices of x for ROWS rows (coalesced float4)
    for (int v = tid; v < ROWS*Ln*(Dn/4); v += 256) {
        int d4 = v & 31; int l = (v >> 5) & 3; int i = v >> 7;
        int r = r0 + i; int b = r >> 9; int n = r & 511;
        float4 val = ((const float4*)(x + (((size_t)(b*Tn + (Tn-1-l))*Nn + n) * Dn)))[d4];
        ((float4*)(&xs[i][l][0]))[d4] = val;
    }
    for (int v = tid; v < ROWS*Dn; v += 256) ((float*)aggbuf)[v] = 0.f;
    __syncthreads();

    for (int l = 0; l < Ln; ++l) {
        // stage W1[l] (128x64)
        for (int v = tid; v < Dn*Hn/4; v += 256)
            ((float4*)wbuf)[v] = ((const float4*)(W1 + (size_t)l*Dn*Hn))[v];
        __syncthreads();
        {   // h = relu(x @ W1 + b1): 8 rows x 64 cols, 2 rows per thread
            int t = tid & 63; int ig = tid >> 6;
            int i0 = ig*2, i1 = i0+1;
            float acc0 = 0.f, acc1 = 0.f;
            for (int d = 0; d < Dn; ++d) {
                float w = wbuf[d*Hn + t];
                acc0 += xs[i0][l][d]*w;
                acc1 += xs[i1][l][d]*w;
            }
            float bb = b1[l*Hn + t];
            hbuf[i0][t] = fmaxf(acc0 + bb, 0.f);
            hbuf[i1][t] = fmaxf(acc1 + bb, 0.f);
        }
        __syncthreads();
        // stage W2[l] (64x128)
        for (int v = tid; v < Hn*Dn/4; v += 256)
            ((float4*)wbuf)[v] = ((const float4*)(W2 + (size_t)l*Hn*Dn))[v];
        __syncthreads();
        {   // enc = h @ W2 + b2, accumulate mean into aggbuf
            int d = tid & 127; int ig = tid >> 7;
            float bb = b2[l*Dn + d];
            #pragma unroll
            for (int ii = 0; ii < 4; ++ii) {
                int i = ig*4 + ii;
                float acc = 0.f;
                for (int h = 0; h < Hn; ++h) acc += hbuf[i][h]*wbuf[h*Dn + d];
                aggbuf[i][d] += (acc + bb)*0.25f;
            }
        }
        __syncthreads();
    }
    {   // projections: sp = agg@Ws1[:D] + bs1, tp = agg@Ws1[D:]
        int k = tid & 127; int ig = tid >> 7;
        float sps[4] = {0,0,0,0}, tps[4] = {0,0,0,0};
        for (int d = 0; d < Dn; ++d) {
            float w_s = Ws1[(size_t)d*Dn + k];
            float w_t = Ws1[(size_t)(Dn + d)*Dn + k];
            #pragma unroll
            for (int ii = 0; ii < 4; ++ii) {
                float a = aggbuf[ig*4+ii][d];
                sps[ii] += a*w_s;
                tps[ii] += a*w_t;
            }
        }
        float bsv = bs1[k];
        #pragma unroll
        for (int ii = 0; ii < 4; ++ii) {
            int r = r0 + ig*4 + ii;
            sp[(size_t)r*Dn + k] = sps[ii] + bsv;   // fold bs1 into sp
            tp[(size_t)r*Dn + k] = tps[ii];
        }
    }
}

// ---------------- K2: pairwise scorer -> thresholded adj ----------------
__global__ __launch_bounds__(256) void k_score(
    const float* __restrict__ sp, const float* __restrict__ tp,
    const float* __restrict__ Ws2, const float* __restrict__ bs2,
    float* __restrict__ adj)
{
    __shared__ float spl[32][132];   // pad 132: i-stride hits distinct banks
    __shared__ float tplT[Dn][36];   // transposed, pad 36 keeps float4 rows 16B-aligned
    __shared__ float w2[Dn];
    int tid = threadIdx.x;
    int b = blockIdx.z;
    int i0 = blockIdx.y * 32, j0 = blockIdx.x * 32;

    for (int v = tid; v < 1024; v += 256) {
        int row = v >> 5, c4 = v & 31;
        ((float4*)(&spl[row][0]))[c4] =
            ((const float4*)(sp + ((size_t)(b*Nn) + i0 + row)*Dn))[c4];
    }
    for (int v = tid; v < 1024; v += 256) {
        int j = v & 31, c4 = v >> 5;
        float4 t = ((const float4*)(tp + ((size_t)(b*Nn) + j0 + j)*Dn))[c4];
        tplT[c4*4+0][j] = t.x; tplT[c4*4+1][j] = t.y;
        tplT[c4*4+2][j] = t.z; tplT[c4*4+3][j] = t.w;
    }
    if (tid < Dn) w2[tid] = Ws2[tid];
    __syncthreads();

    int iL = tid >> 3;    // 0..31
    int jq = tid & 7;     // 4 consecutive j per thread
    float acc[4] = {0,0,0,0};
    #pragma unroll 4
    for (int k = 0; k < Dn; ++k) {
        float s = spl[iL][k];
        float w = w2[k];
        float4 t4 = *(const float4*)&tplT[k][jq*4];
        acc[0] += fmaxf(s + t4.x, 0.f)*w;
        acc[1] += fmaxf(s + t4.y, 0.f)*w;
        acc[2] += fmaxf(s + t4.z, 0.f)*w;
        acc[3] += fmaxf(s + t4.w, 0.f)*w;
    }
    float bsv = bs2[0];
    int i = i0 + iL;
    int jbase = j0 + jq*4;
    float r[4];
    #pragma unroll
    for (int u = 0; u < 4; ++u) {
        float z = acc[u] + bsv;
        float sc = 1.f/(1.f + __expf(-z));
        int j = jbase + u;
        r[u] = (sc > 0.1f && i != j) ? sc : 0.f;   // threshold + zero diagonal
    }
    *(float4*)(adj + (size_t)b*NNe + (size_t)i*Nn + jbase) = make_float4(r[0], r[1], r[2], r[3]);
}

// ---------------- K3: a2 = adj @ adj (fp32, 64x64 tile, 4x4 micro) ----------------
__global__ __launch_bounds__(256) void k_mm1(const float* __restrict__ adj, float* __restrict__ a2)
{
    __shared__ float As[16][68];   // A^T tile: [k][i], pad 68 (16B-aligned rows, 2-way writes)
    __shared__ float Bs[16][68];
    int tid = threadIdx.x;
    int b = blockIdx.z;
    int i0 = blockIdx.y * 64, j0 = blockIdx.x * 64;
    const float* Ab = adj + (size_t)b*NNe;
    int tx = tid & 15, ty = tid >> 4;
    int ar = tid >> 2, ac4 = tid & 3;
    int bk = tid >> 4, bj4 = tid & 15;
    float acc[4][4] = {};
    float4 a = *(const float4*)(Ab + (size_t)(i0 + ar)*Nn + ac4*4);
    float4 bb = *(const float4*)(Ab + (size_t)bk*Nn + j0 + bj4*4);
    for (int kt = 0; kt < Nn; kt += 16) {
        As[ac4*4+0][ar] = a.x; As[ac4*4+1][ar] = a.y;
        As[ac4*4+2][ar] = a.z; As[ac4*4+3][ar] = a.w;
        *(float4*)&Bs[bk][bj4*4] = bb;
        __syncthreads();
        if (kt + 16 < Nn) {   // prefetch next K-tile while computing this one
            a  = *(const float4*)(Ab + (size_t)(i0 + ar)*Nn + (kt+16) + ac4*4);
            bb = *(const float4*)(Ab + (size_t)(kt+16 + bk)*Nn + j0 + bj4*4);
        }
        #pragma unroll
        for (int k = 0; k < 16; ++k) {
            float4 a4 = *(const float4*)&As[k][ty*4];
            float4 b4 = *(const float4*)&Bs[k][tx*4];
            float av[4] = {a4.x, a4.y, a4.z, a4.w};
            float bv[4] = {b4.x, b4.y, b4.z, b4.w};
            #pragma unroll
            for (int u = 0; u < 4; ++u)
                #pragma unroll
                for (int v = 0; v < 4; ++v)
                    acc[u][v] += av[u]*bv[v];
        }
        __syncthreads();
    }
    float* Cb = a2 + (size_t)b*NNe;
    #pragma unroll
    for (int u = 0; u < 4; ++u)
        *(float4*)(Cb + (size_t)(i0 + ty*4 + u)*Nn + j0 + tx*4) =
            make_float4(acc[u][0], acc[u][1], acc[u][2], acc[u][3]);
}

// ---------------- K4: enhanced = adj + 0.5*a2 + 0.25*(a2@adj), + per-batch max ----------------
__global__ __launch_bounds__(256) void k_mm2(
    const float* __restrict__ adj, const float* __restrict__ a2,
    float* __restrict__ out, unsigned int* __restrict__ maxslot)
{
    __shared__ float As[16][68];
    __shared__ float Bs[16][68];
    int tid = threadIdx.x;
    int b = blockIdx.z;
    int i0 = blockIdx.y * 64, j0 = blockIdx.x * 64;
    const float* Ab = a2  + (size_t)b*NNe;   // A = a2
    const float* Bb = adj + (size_t)b*NNe;   // B = adj
    int tx = tid & 15, ty = tid >> 4;
    int ar = tid >> 2, ac4 = tid & 3;
    int bk = tid >> 4, bj4 = tid & 15;
    float acc[4][4] = {};
    float4 a = *(const float4*)(Ab + (size_t)(i0 + ar)*Nn + ac4*4);
    float4 bb = *(const float4*)(Bb + (size_t)bk*Nn + j0 + bj4*4);
    for (int kt = 0; kt < Nn; kt += 16) {
        As[ac4*4+0][ar] = a.x; As[ac4*4+1][ar] = a.y;
        As[ac4*4+2][ar] = a.z; As[ac4*4+3][ar] = a.w;
        *(float4*)&Bs[bk][bj4*4] = bb;
        __syncthreads();
        if (kt + 16 < Nn) {
            a  = *(const float4*)(Ab + (size_t)(i0 + ar)*Nn + (kt+16) + ac4*4);
            bb = *(const float4*)(Bb + (size_t)(kt+16 + bk)*Nn + j0 + bj4*4);
        }
        #pragma unroll
        for (int k = 0; k < 16; ++k) {
            float4 a4 = *(const float4*)&As[k][ty*4];
            float4 b4 = *(const float4*)&Bs[k][tx*4];
            float av[4] = {a4.x, a4.y, a4.z, a4.w};
            float bv[4] = {b4.x, b4.y, b4.z, b4.w};
            #pragma unroll
            for (int u = 0; u < 4; ++u)
                #pragma unroll
                for (int v = 0; v < 4; ++v)
                    acc[u][v] += av[u]*bv[v];
        }
        __syncthreads();
    }
    float* Ob = out + (size_t)b*NNe;
    float lmax = 0.f;
    #pragma unroll
    for (int u = 0; u < 4; ++u) {
        size_t off = (size_t)(i0 + ty*4 + u)*Nn + j0 + tx*4;
        float4 av = *(const float4*)(Bb + off);   // adj
        float4 pv = *(const float4*)(Ab + off);   // a2
        float4 e;
        e.x = av.x + 0.5f*pv.x + 0.25f*acc[u][0];
        e.y = av.y + 0.5f*pv.y + 0.25f*acc[u][1];
        e.z = av.z + 0.5f*pv.z + 0.25f*acc[u][2];
        e.w = av.w + 0.5f*pv.w + 0.25f*acc[u][3];
        *(float4*)(Ob + off) = e;
        lmax = fmaxf(lmax, fmaxf(fmaxf(e.x, e.y), fmaxf(e.z, e.w)));
    }
    // block max reduction (values >= 0 so uint-compare atomicMax is order-preserving)
    #pragma unroll
    for (int s = 1; s < 64; s <<= 1) lmax = fmaxf(lmax, __shfl_xor(lmax, s, 64));
    __shared__ float red[4];
    int lane = tid & 63, wv = tid >> 6;
    if (lane == 0) red[wv] = lmax;
    __syncthreads();
    if (tid == 0) {
        float m = fmaxf(fmaxf(red[0], red[1]), fmaxf(red[2], red[3]));
        atomicMax(maxslot + b, __float_as_uint(m));
    }
}

// ---------------- K5: out /= (max + 1e-8) ----------------
__global__ __launch_bounds__(256) void k_norm(float* __restrict__ out,
                                              const unsigned int* __restrict__ maxslot)
{
    int idx = blockIdx.x*256 + threadIdx.x;   // float4 index; NNe/4 = 65536 per batch
    int b = idx >> 16;
    float m = __uint_as_float(maxslot[b]);
    float inv = 1.f/(m + 1e-8f);
    float4* p = (float4*)out + idx;
    float4 v = *p;
    v.x *= inv; v.y *= inv; v.z *= inv; v.w *= inv;
    *p = v;
}

extern "C" void kernel_launch(void* const* d_in, const int* in_sizes, int n_in,
                              void* d_out, int out_size, void* d_ws, size_t ws_size,
                              hipStream_t stream) {
    const float* x   = (const float*)d_in[0];
    const float* W1  = (const float*)d_in[1];
    const float* b1  = (const float*)d_in[2];
    const float* W2  = (const float*)d_in[3];
    const float* b2  = (const float*)d_in[4];
    const float* Ws1 = (const float*)d_in[5];
    const float* bs1 = (const float*)d_in[6];
    const float* Ws2 = (const float*)d_in[7];
    const float* bs2 = (const float*)d_in[8];
    float* out = (float*)d_out;

    float* ws  = (float*)d_ws;
    float* sp  = ws;                          // B*N*D = 262144
    float* tp  = sp + (size_t)Bn*Nn*Dn;       // 262144
    float* adj = tp + (size_t)Bn*Nn*Dn;       // B*N*N = 1048576
    float* a2  = adj + (size_t)Bn*NNe;        // 1048576
    unsigned int* maxslot = (unsigned int*)(a2 + (size_t)Bn*NNe);  // 4

    k_encode<<<dim3(Bn*Nn/ROWS), 256, 0, stream>>>(x, W1, b1, W2, b2, Ws1, bs1, sp, tp, maxslot);
    k_score <<<dim3(16, 16, Bn), 256, 0, stream>>>(sp, tp, Ws2, bs2, adj);
    k_mm1   <<<dim3(8, 8, Bn),   256, 0, stream>>>(adj, a2);
    k_mm2   <<<dim3(8, 8, Bn),   256, 0, stream>>>(adj, a2, out, maxslot);
    k_norm  <<<dim3(Bn*NNe/4/256), 256, 0, stream>>>(out, maxslot);
}

// Round 3
// 161.117 us; speedup vs baseline: 1.0781x; 1.0781x over previous
//
#include <hip/hip_runtime.h>
#include <math.h>

#define Bn 4
#define Tn 12
#define Nn 512
#define Dn 128
#define Ln 4
#define Hn 64
#define NNe (Nn*Nn)

typedef __attribute__((ext_vector_type(8))) short short8;
typedef __attribute__((ext_vector_type(4))) float f32x4;

__device__ __forceinline__ unsigned short f2bf(float f) {
    unsigned int u = __float_as_uint(f);
    unsigned int r = (u + 0x7FFF + ((u >> 16) & 1)) >> 16;   // RNE
    return (unsigned short)r;
}
__device__ __forceinline__ float bf2f(unsigned short s) {
    return __uint_as_float(((unsigned int)s) << 16);
}

// ---------------- K1a: h = relu(x_lag @ W1[l] + b1[l]) ----------------
// wave = (lag, row-quad); lane = h-channel. x via wave-uniform (scalar-path) loads.
__global__ __launch_bounds__(256) void k_enc_a(
    const float* __restrict__ x, const float* __restrict__ W1, const float* __restrict__ b1,
    float* __restrict__ h, unsigned int* __restrict__ maxslot)
{
    int tid = threadIdx.x;
    if (blockIdx.x == 0 && tid < Bn) maxslot[tid] = 0u;
    int wv = __builtin_amdgcn_readfirstlane(tid >> 6);
    int lane = tid & 63;
    int flat = blockIdx.x * 4 + wv;          // 0..2047
    int lag  = flat >> 9;                    // 4 waves of a block share a lag -> L1-friendly
    int quad = flat & 511;
    int r0 = quad * 4;                       // global row in [0, B*N)
    int bb = r0 >> 9, n0 = r0 & 511;
    const float* xr = x + ((size_t)(bb*Tn + (Tn-1-lag))*Nn + n0) * Dn;   // 4 rows contiguous (+128)
    const float* Wp = W1 + (size_t)lag * Dn * Hn;
    float acc[4] = {0.f, 0.f, 0.f, 0.f};
    for (int d4 = 0; d4 < 32; ++d4) {
        float4 xv[4];
        #pragma unroll
        for (int r = 0; r < 4; ++r) xv[r] = *(const float4*)(xr + r*Dn + d4*4);   // uniform -> s_load
        #pragma unroll
        for (int u = 0; u < 4; ++u) {
            float w = Wp[(d4*4 + u)*Hn + lane];
            #pragma unroll
            for (int r = 0; r < 4; ++r) acc[r] += ((const float*)&xv[r])[u] * w;
        }
    }
    float bv = b1[lag*Hn + lane];
    float* hp = h + ((size_t)lag*2048 + r0) * Hn + lane;
    #pragma unroll
    for (int r = 0; r < 4; ++r) hp[r*Hn] = fmaxf(acc[r] + bv, 0.f);
}

// ---------------- K1b: agg = 0.25 * sum_l (h_l @ W2[l] + b2[l]) ----------------
// wave = row-pair, all 4 lags; lane owns d and d+64. h via scalar-path loads.
__global__ __launch_bounds__(256) void k_enc_b(
    const float* __restrict__ h, const float* __restrict__ W2, const float* __restrict__ b2,
    float* __restrict__ agg)
{
    int tid = threadIdx.x;
    int wv = __builtin_amdgcn_readfirstlane(tid >> 6);
    int lane = tid & 63;
    int flat = blockIdx.x * 4 + wv;          // 0..1023
    int r0 = flat * 2;
    float a00 = 0.f, a01 = 0.f, a10 = 0.f, a11 = 0.f;   // [row][d-half]
    for (int l = 0; l < Ln; ++l) {
        const float* Wp = W2 + (size_t)l * Hn * Dn;
        const float* h0 = h + ((size_t)l*2048 + r0) * Hn;
        const float* h1 = h0 + Hn;
        for (int h4 = 0; h4 < 16; ++h4) {
            float4 hv0 = *(const float4*)(h0 + h4*4);   // uniform -> s_load
            float4 hv1 = *(const float4*)(h1 + h4*4);
            #pragma unroll
            for (int u = 0; u < 4; ++u) {
                float w0 = Wp[(h4*4 + u)*Dn + lane];
                float w1 = Wp[(h4*4 + u)*Dn + lane + 64];
                float x0 = ((const float*)&hv0)[u];
                float x1 = ((const float*)&hv1)[u];
                a00 += x0*w0; a01 += x0*w1; a10 += x1*w0; a11 += x1*w1;
            }
        }
    }
    float b2s0 = b2[lane]      + b2[Dn+lane]      + b2[2*Dn+lane]      + b2[3*Dn+lane];
    float b2s1 = b2[lane+64]   + b2[Dn+lane+64]   + b2[2*Dn+lane+64]   + b2[3*Dn+lane+64];
    agg[(size_t)r0*Dn + lane]          = 0.25f*(a00 + b2s0);
    agg[(size_t)r0*Dn + lane + 64]     = 0.25f*(a01 + b2s1);
    agg[(size_t)(r0+1)*Dn + lane]      = 0.25f*(a10 + b2s0);
    agg[(size_t)(r0+1)*Dn + lane + 64] = 0.25f*(a11 + b2s1);
}

// ---------------- K1c: sp = agg@Ws1[:D] + bs1, tp = agg@Ws1[D:] ----------------
// block = 128 threads (2 waves); wave = row-quad; lane owns k and k+64 for sp and tp.
__global__ __launch_bounds__(128) void k_proj(
    const float* __restrict__ agg, const float* __restrict__ Ws1, const float* __restrict__ bs1,
    float* __restrict__ sp, float* __restrict__ tp)
{
    int tid = threadIdx.x;
    int wv = __builtin_amdgcn_readfirstlane(tid >> 6);
    int lane = tid & 63;
    int flat = blockIdx.x * 2 + wv;          // 0..511
    int r0 = flat * 4;
    float acc[4][4] = {};                    // [row][{sp_k, sp_k64, tp_k, tp_k64}]
    const float* a0 = agg + (size_t)r0 * Dn;
    for (int d4 = 0; d4 < 32; ++d4) {
        float4 av[4];
        #pragma unroll
        for (int r = 0; r < 4; ++r) av[r] = *(const float4*)(a0 + r*Dn + d4*4);  // uniform
        #pragma unroll
        for (int u = 0; u < 4; ++u) {
            int d = d4*4 + u;
            float ws0 = Ws1[(size_t)d*Dn + lane];
            float ws1 = Ws1[(size_t)d*Dn + lane + 64];
            float wt0 = Ws1[(size_t)(Dn + d)*Dn + lane];
            float wt1 = Ws1[(size_t)(Dn + d)*Dn + lane + 64];
            #pragma unroll
            for (int r = 0; r < 4; ++r) {
                float a = ((const float*)&av[r])[u];
                acc[r][0] += a*ws0; acc[r][1] += a*ws1;
                acc[r][2] += a*wt0; acc[r][3] += a*wt1;
            }
        }
    }
    float bv0 = bs1[lane], bv1 = bs1[lane + 64];
    #pragma unroll
    for (int r = 0; r < 4; ++r) {
        size_t ro = (size_t)(r0 + r) * Dn;
        sp[ro + lane]      = acc[r][0] + bv0;   // bs1 folded into sp
        sp[ro + lane + 64] = acc[r][1] + bv1;
        tp[ro + lane]      = acc[r][2];
        tp[ro + lane + 64] = acc[r][3];
    }
}

// ---------------- K2: pairwise scorer -> adj (bf16, row-major + transposed) ----------------
// block: 64 i x 64 j; wave: 16 i x 64 j; lane: 4 i x 4 j (acc[4][4]).
__global__ __launch_bounds__(256) void k_score(
    const float* __restrict__ sp, const float* __restrict__ tp,
    const float* __restrict__ Ws2, const float* __restrict__ bs2,
    unsigned short* __restrict__ adj_b, unsigned short* __restrict__ adj_bt)
{
    __shared__ float spl[64][132];    // pad 132: iq-group rows land on distinct banks
    __shared__ float tplT[Dn][64];    // [k][j]
    int tid = threadIdx.x;
    int wv = __builtin_amdgcn_readfirstlane(tid >> 6);
    int lane = tid & 63;
    int b = blockIdx.z;
    int i0b = blockIdx.y * 64, j0b = blockIdx.x * 64;

    // stage sp tile (64 x 128 fp32) -- FIXED: full 2048 float4 chunks, contiguous
    for (int v = tid; v < 2048; v += 256) {
        int row = v >> 5, c4 = v & 31;
        *(float4*)&spl[row][c4*4] = *(const float4*)(sp + ((size_t)(b*Nn) + i0b + row)*Dn + c4*4);
    }
    // stage tp tile transposed: tplT[k][j]
    {
        int j = tid & 63, kq = tid >> 6;
        for (int p = 0; p < 8; ++p) {
            int k4 = p*4 + kq;        // 0..31
            float4 t = *(const float4*)(tp + ((size_t)(b*Nn) + j0b + j)*Dn + k4*4);
            tplT[k4*4+0][j] = t.x; tplT[k4*4+1][j] = t.y;
            tplT[k4*4+2][j] = t.z; tplT[k4*4+3][j] = t.w;
        }
    }
    __syncthreads();

    int iq = lane >> 4, jq = lane & 15;
    float acc[4][4] = {};
    for (int k4 = 0; k4 < 32; ++k4) {
        float4 w4 = *(const float4*)(Ws2 + k4*4);     // uniform -> scalar path
        float4 s4[4], t4[4];
        #pragma unroll
        for (int ii = 0; ii < 4; ++ii) s4[ii] = *(const float4*)&spl[wv*16 + iq*4 + ii][k4*4];
        #pragma unroll
        for (int kk = 0; kk < 4; ++kk) t4[kk] = *(const float4*)&tplT[k4*4 + kk][jq*4];
        #pragma unroll
        for (int kk = 0; kk < 4; ++kk) {
            float w = ((const float*)&w4)[kk];
            #pragma unroll
            for (int ii = 0; ii < 4; ++ii) {
                float s = ((const float*)&s4[ii])[kk];
                #pragma unroll
                for (int jj = 0; jj < 4; ++jj)
                    acc[ii][jj] += fmaxf(s + ((const float*)&t4[kk])[jj], 0.f) * w;
            }
        }
    }
    float bsv = bs2[0];
    int i0 = i0b + wv*16 + iq*4;
    int j0 = j0b + jq*4;
    float vals[4][4];
    #pragma unroll
    for (int ii = 0; ii < 4; ++ii) {
        int i = i0 + ii;
        #pragma unroll
        for (int jj = 0; jj < 4; ++jj) {
            float z = acc[ii][jj] + bsv;
            float sc = 1.f/(1.f + __expf(-z));
            int j = j0 + jj;
            vals[ii][jj] = (sc > 0.1f && i != j) ? sc : 0.f;
        }
    }
    size_t base = (size_t)b << 18;
    #pragma unroll
    for (int ii = 0; ii < 4; ++ii) {
        ushort4 rv = make_ushort4(f2bf(vals[ii][0]), f2bf(vals[ii][1]), f2bf(vals[ii][2]), f2bf(vals[ii][3]));
        *(ushort4*)(adj_b + base + (size_t)(i0 + ii)*Nn + j0) = rv;
    }
    #pragma unroll
    for (int jj = 0; jj < 4; ++jj) {
        ushort4 cv = make_ushort4(f2bf(vals[0][jj]), f2bf(vals[1][jj]), f2bf(vals[2][jj]), f2bf(vals[3][jj]));
        *(ushort4*)(adj_bt + base + (size_t)(j0 + jj)*Nn + i0) = cv;
    }
}

// ---------------- K3: a2 = adj @ adj via bf16 MFMA (128x128 block, 64x64 wave) ----------------
__global__ __launch_bounds__(256) void k_mm1(
    const unsigned short* __restrict__ adj_b, const unsigned short* __restrict__ adj_bt,
    unsigned short* __restrict__ a2b)
{
    __shared__ unsigned short Als[128*32];
    __shared__ unsigned short Bls[128*32];
    int tid = threadIdx.x;
    int wv = __builtin_amdgcn_readfirstlane(tid >> 6);
    int lane = tid & 63;
    int b = blockIdx.z, it = blockIdx.y, jt = blockIdx.x;
    size_t base = (size_t)b << 18;
    const unsigned short* Ab = adj_b + base;
    const unsigned short* Bb = adj_bt + base;
    int wm = wv >> 1, wn = wv & 1;
    int q = lane >> 4, m = lane & 15;
    f32x4 acc[4][4];
    #pragma unroll
    for (int mt = 0; mt < 4; ++mt)
        #pragma unroll
        for (int nt = 0; nt < 4; ++nt) acc[mt][nt] = (f32x4){0.f, 0.f, 0.f, 0.f};

    for (int kt = 0; kt < 16; ++kt) {
        int k0 = kt * 32;
        __syncthreads();
        #pragma unroll
        for (int p = 0; p < 2; ++p) {
            int c = tid + p*256;                 // 0..511 16B-chunks
            int r = c >> 2, cc = c & 3;
            *(float4*)&Als[r*32 + cc*8] = *(const float4*)(Ab + (size_t)(it*128 + r)*Nn + k0 + cc*8);
            *(float4*)&Bls[r*32 + cc*8] = *(const float4*)(Bb + (size_t)(jt*128 + r)*Nn + k0 + cc*8);
        }
        __syncthreads();
        short8 af[4], bf[4];
        #pragma unroll
        for (int mt = 0; mt < 4; ++mt) af[mt] = *(const short8*)&Als[(wm*64 + mt*16 + m)*32 + q*8];
        #pragma unroll
        for (int nt = 0; nt < 4; ++nt) bf[nt] = *(const short8*)&Bls[(wn*64 + nt*16 + m)*32 + q*8];
        #pragma unroll
        for (int mt = 0; mt < 4; ++mt)
            #pragma unroll
            for (int nt = 0; nt < 4; ++nt)
                acc[mt][nt] = __builtin_amdgcn_mfma_f32_16x16x32_bf16(af[mt], bf[nt], acc[mt][nt], 0, 0, 0);
    }
    int col = lane & 15, rq = lane >> 4;
    #pragma unroll
    for (int mt = 0; mt < 4; ++mt)
        #pragma unroll
        for (int nt = 0; nt < 4; ++nt)
            #pragma unroll
            for (int reg = 0; reg < 4; ++reg) {
                int i = it*128 + wm*64 + mt*16 + rq*4 + reg;
                int j = jt*128 + wn*64 + nt*16 + col;
                a2b[base + (size_t)i*Nn + j] = f2bf(acc[mt][nt][reg]);
            }
}

// ---------------- K4: out = adj + 0.5*a2 + 0.25*(a2@adj), + per-batch max ----------------
__global__ __launch_bounds__(256) void k_mm2(
    const unsigned short* __restrict__ adj_b, const unsigned short* __restrict__ adj_bt,
    const unsigned short* __restrict__ a2b,
    float* __restrict__ out, unsigned int* __restrict__ maxslot)
{
    __shared__ unsigned short Als[128*32];
    __shared__ unsigned short Bls[128*32];
    int tid = threadIdx.x;
    int wv = __builtin_amdgcn_readfirstlane(tid >> 6);
    int lane = tid & 63;
    int b = blockIdx.z, it = blockIdx.y, jt = blockIdx.x;
    size_t base = (size_t)b << 18;
    const unsigned short* Ab = a2b + base;       // A = a2
    const unsigned short* Bb = adj_bt + base;    // B = adj (transposed layout)
    int wm = wv >> 1, wn = wv & 1;
    int q = lane >> 4, m = lane & 15;
    f32x4 acc[4][4];
    #pragma unroll
    for (int mt = 0; mt < 4; ++mt)
        #pragma unroll
        for (int nt = 0; nt < 4; ++nt) acc[mt][nt] = (f32x4){0.f, 0.f, 0.f, 0.f};

    for (int kt = 0; kt < 16; ++kt) {
        int k0 = kt * 32;
        __syncthreads();
        #pragma unroll
        for (int p = 0; p < 2; ++p) {
            int c = tid + p*256;
            int r = c >> 2, cc = c & 3;
            *(float4*)&Als[r*32 + cc*8] = *(const float4*)(Ab + (size_t)(it*128 + r)*Nn + k0 + cc*8);
            *(float4*)&Bls[r*32 + cc*8] = *(const float4*)(Bb + (size_t)(jt*128 + r)*Nn + k0 + cc*8);
        }
        __syncthreads();
        short8 af[4], bf[4];
        #pragma unroll
        for (int mt = 0; mt < 4; ++mt) af[mt] = *(const short8*)&Als[(wm*64 + mt*16 + m)*32 + q*8];
        #pragma unroll
        for (int nt = 0; nt < 4; ++nt) bf[nt] = *(const short8*)&Bls[(wn*64 + nt*16 + m)*32 + q*8];
        #pragma unroll
        for (int mt = 0; mt < 4; ++mt)
            #pragma unroll
            for (int nt = 0; nt < 4; ++nt)
                acc[mt][nt] = __builtin_amdgcn_mfma_f32_16x16x32_bf16(af[mt], bf[nt], acc[mt][nt], 0, 0, 0);
    }
    int col = lane & 15, rq = lane >> 4;
    float lmax = 0.f;
    const unsigned short* adjp = adj_b + base;
    #pragma unroll
    for (int mt = 0; mt < 4; ++mt)
        #pragma unroll
        for (int nt = 0; nt < 4; ++nt)
            #pragma unroll
            for (int reg = 0; reg < 4; ++reg) {
                int i = it*128 + wm*64 + mt*16 + rq*4 + reg;
                int j = jt*128 + wn*64 + nt*16 + col;
                size_t off = (size_t)i*Nn + j;
                float e = bf2f(adjp[off]) + 0.5f*bf2f(Ab[off]) + 0.25f*acc[mt][nt][reg];
                out[base + off] = e;
                lmax = fmaxf(lmax, e);
            }
    #pragma unroll
    for (int s = 1; s < 64; s <<= 1) lmax = fmaxf(lmax, __shfl_xor(lmax, s, 64));
    __shared__ float red[4];
    if (lane == 0) red[wv] = lmax;
    __syncthreads();
    if (tid == 0) {
        float mx = fmaxf(fmaxf(red[0], red[1]), fmaxf(red[2], red[3]));
        atomicMax(maxslot + b, __float_as_uint(mx));
    }
}

// ---------------- K5: out /= (max + 1e-8) ----------------
__global__ __launch_bounds__(256) void k_norm(float* __restrict__ out,
                                              const unsigned int* __restrict__ maxslot)
{
    int idx = blockIdx.x*256 + threadIdx.x;   // float4 index; NNe/4 = 65536 per batch
    int b = idx >> 16;
    float m = __uint_as_float(maxslot[b]);
    float inv = 1.f/(m + 1e-8f);
    float4* p = (float4*)out + idx;
    float4 v = *p;
    v.x *= inv; v.y *= inv; v.z *= inv; v.w *= inv;
    *p = v;
}

extern "C" void kernel_launch(void* const* d_in, const int* in_sizes, int n_in,
                              void* d_out, int out_size, void* d_ws, size_t ws_size,
                              hipStream_t stream) {
    const float* x   = (const float*)d_in[0];
    const float* W1  = (const float*)d_in[1];
    const float* b1  = (const float*)d_in[2];
    const float* W2  = (const float*)d_in[3];
    const float* b2  = (const float*)d_in[4];
    const float* Ws1 = (const float*)d_in[5];
    const float* bs1 = (const float*)d_in[6];
    const float* Ws2 = (const float*)d_in[7];
    const float* bs2 = (const float*)d_in[8];
    float* out = (float*)d_out;

    float* ws = (float*)d_ws;
    float* sp  = ws;                              // 262144 f
    float* tp  = ws + 262144;                     // 262144 f
    float* h   = ws + 524288;                     // 524288 f (dead after k_enc_b)
    float* agg = ws + 1048576;                    // 262144 f (dead after k_proj)
    unsigned short* adj_b  = (unsigned short*)(ws + 524288);    // 1M bf16, overlays dead h
    unsigned short* adj_bt = (unsigned short*)(ws + 1048576);   // 1M bf16, overlays dead agg
    unsigned short* a2b    = (unsigned short*)(ws + 1572864);   // 1M bf16
    unsigned int* maxslot  = (unsigned int*)(ws + 2097152);     // 4

    k_enc_a<<<dim3(512), 256, 0, stream>>>(x, W1, b1, h, maxslot);
    k_enc_b<<<dim3(256), 256, 0, stream>>>(h, W2, b2, agg);
    k_proj <<<dim3(256), 128, 0, stream>>>(agg, Ws1, bs1, sp, tp);
    k_score<<<dim3(8, 8, Bn), 256, 0, stream>>>(sp, tp, Ws2, bs2, adj_b, adj_bt);
    k_mm1  <<<dim3(4, 4, Bn), 256, 0, stream>>>(adj_b, adj_bt, a2b);
    k_mm2  <<<dim3(4, 4, Bn), 256, 0, stream>>>(adj_b, adj_bt, a2b, out, maxslot);
    k_norm <<<dim3(Bn*NNe/4/256), 256, 0, stream>>>(out, maxslot);
}